// Round 1
// baseline (2302.599 us; speedup 1.0000x reference)
//
#include <hip/hip_runtime.h>
#include <cstdint>

#define B_SZ   512
#define IN_SZ  3072
#define HID    2048
#define OUT_SZ 512
#define T_STEPS 10
#define NELEM  (512u*3072u)          // 1572864
#define BITS_T_STRIDE (512u*96u)     // words per timestep (96 words/row)

struct Keys { uint32_t k[2*T_STEPS]; };

__host__ __device__ inline void threefry2x32(uint32_t k0, uint32_t k1,
                                             uint32_t x0, uint32_t x1,
                                             uint32_t& y0, uint32_t& y1) {
  const uint32_t ks2 = k0 ^ k1 ^ 0x1BD11BDAu;
#define TF_R(r) { x0 += x1; x1 = (x1 << (r)) | (x1 >> (32-(r))); x1 ^= x0; }
  x0 += k0; x1 += k1;
  TF_R(13) TF_R(15) TF_R(26) TF_R(6)   x0 += k1;  x1 += ks2 + 1u;
  TF_R(17) TF_R(29) TF_R(16) TF_R(24)  x0 += ks2; x1 += k0  + 2u;
  TF_R(13) TF_R(15) TF_R(26) TF_R(6)   x0 += k0;  x1 += k1  + 3u;
  TF_R(17) TF_R(29) TF_R(16) TF_R(24)  x0 += k1;  x1 += ks2 + 4u;
  TF_R(13) TF_R(15) TF_R(26) TF_R(6)   x0 += ks2; x1 += k0  + 5u;
#undef TF_R
  y0 = x0; y1 = x1;
}

// ---------------- spike generation: all T steps of input Bernoulli bits ----
__global__ __launch_bounds__(256) void spikegen_kernel(
    const float* __restrict__ x, uint32_t* __restrict__ pre_bits, Keys keys) {
  uint32_t m = blockIdx.x * 256u + threadIdx.x;   // flat index into [512][3072]
  uint32_t b = m / IN_SZ;
  uint32_t j = m - b * IN_SZ;
  float xv = x[m];
  // sigmoid in f64, round to f32 (canonical / correctly rounded)
  float p = (float)(1.0 / (1.0 + exp(-(double)xv)));
  uint32_t lane = threadIdx.x & 63u;
  uint32_t wbase = b * 96u + (j >> 5);            // wave-uniform (j0 % 64 == 0)
#pragma unroll
  for (int t = 0; t < T_STEPS; ++t) {
    uint32_t y0, y1;
    // partitionable path: bits = y0 ^ y1 of threefry(key_t, (hi=0, lo=m))
    threefry2x32(keys.k[2*t], keys.k[2*t+1], 0u, m, y0, y1);
    uint32_t bits = y0 ^ y1;
    float u = __uint_as_float((bits >> 9) | 0x3f800000u) - 1.0f;
    unsigned long long mask = __ballot(u < p);
    if (lane == 0u) {
      *reinterpret_cast<unsigned long long*>(
          &pre_bits[(uint32_t)t * BITS_T_STRIDE + wbase]) = mask;
    }
  }
}

// ---------------- transpose (tiled) ---------------------------------------
__global__ void transpose_kernel(const float* __restrict__ in,
                                 float* __restrict__ out, int rows, int cols) {
  __shared__ float tile[32][33];
  int c0 = blockIdx.x * 32, r0 = blockIdx.y * 32;
  int tx = threadIdx.x, ty = threadIdx.y;   // block (32, 8)
#pragma unroll
  for (int i = 0; i < 32; i += 8)
    tile[ty + i][tx] = in[(size_t)(r0 + ty + i) * cols + c0 + tx];
  __syncthreads();
#pragma unroll
  for (int i = 0; i < 32; i += 8)
    out[(size_t)(c0 + ty + i) * rows + r0 + tx] = tile[tx][ty + i];
}

// ---------------- hidden layer: h = pre @ Win^T, LIF, spikes --------------
__global__ __launch_bounds__(256) void hidden_kernel(
    const float* __restrict__ WinT,        // [3072][2048]
    const uint32_t* __restrict__ pre_bits, // [T][512][96]
    float* __restrict__ v,                 // [512][2048]
    float* __restrict__ spikes,            // [512][2048] (0.0/1.0)
    int t) {
  __shared__ __align__(16) float At[32 * 68];  // [k][b], pad 68 keeps 16B align
  __shared__ __align__(16) float Bt[32 * 64];  // [k][n]
  __shared__ uint32_t lw[64];
  int tid = threadIdx.x;
  int n0 = blockIdx.x * 64;
  int b0 = blockIdx.y * 64;
  int tn = tid & 15, tb = tid >> 4;
  float acc[4][4] = {};
  const uint32_t* bits_t = pre_bits + (uint32_t)t * BITS_T_STRIDE;

  for (int kc = 0; kc < 96; ++kc) {
    __syncthreads();   // previous inner-loop reads done
    if (tid < 64) lw[tid] = bits_t[(b0 + tid) * 96 + kc];
    {  // stage W tile: rows kc*32..+31, cols n0..n0+63
      int kr = tid >> 6, nn = tid & 63;
#pragma unroll
      for (int rr = 0; rr < 32; rr += 4)
        Bt[(kr + rr) * 64 + nn] =
            WinT[(size_t)(kc * 32 + kr + rr) * HID + n0 + nn];
    }
    __syncthreads();   // lw ready
    {  // expand bits -> f32 A tile
      int bb = tid & 63, kb = (tid >> 6) * 8;
      uint32_t w = lw[bb];
#pragma unroll
      for (int q = 0; q < 8; ++q)
        At[(kb + q) * 68 + bb] = (float)((w >> (kb + q)) & 1u);
    }
    __syncthreads();   // tiles ready
#pragma unroll
    for (int kk = 0; kk < 32; ++kk) {
      float a_[4], w_[4];
      *(float4*)a_ = *(const float4*)&At[kk * 68 + tb * 4];
      *(float4*)w_ = *(const float4*)&Bt[kk * 64 + tn * 4];
#pragma unroll
      for (int i = 0; i < 4; ++i)
#pragma unroll
        for (int jj = 0; jj < 4; ++jj)
          acc[i][jj] = fmaf(a_[i], w_[jj], acc[i][jj]);
    }
  }

  {  // LIF epilogue — NO fp contraction: v*0.3f then +h, separate roundings
#pragma clang fp contract(off)
#pragma unroll
    for (int i = 0; i < 4; ++i) {
      int b = b0 + tb * 4 + i;
      size_t base = (size_t)b * HID + n0 + tn * 4;
      float vprev[4] = {0.f, 0.f, 0.f, 0.f};
      if (t > 0) {
        float4 vp = *(const float4*)&v[base];
        vprev[0] = vp.x; vprev[1] = vp.y; vprev[2] = vp.z; vprev[3] = vp.w;
      }
      float vn_[4], sp_[4];
#pragma unroll
      for (int jj = 0; jj < 4; ++jj) {
        float vd = vprev[jj] * 0.3f;
        float vn = vd + acc[i][jj];
        bool sp = (vn >= 1.0f);
        vn_[jj] = sp ? 0.0f : vn;
        sp_[jj] = sp ? 1.0f : 0.0f;
      }
      *(float4*)&v[base]      = make_float4(vn_[0], vn_[1], vn_[2], vn_[3]);
      *(float4*)&spikes[base] = make_float4(sp_[0], sp_[1], sp_[2], sp_[3]);
    }
  }
}

// ---------------- output layer: out = spikes @ Wout^T + b, count ----------
__global__ __launch_bounds__(256) void out_kernel(
    const float* __restrict__ WoutT,   // [2048][512]
    const float* __restrict__ spikes,  // [512][2048]
    const float* __restrict__ b_out,   // [512]
    float* __restrict__ s,             // [512][512] = d_out
    int t) {
  __shared__ __align__(16) float At[32 * 34];  // [k][b], pad 34 keeps 8B align
  __shared__ __align__(16) float Bt[32 * 32];  // [k][o]
  int tid = threadIdx.x;
  int o0 = blockIdx.x * 32;
  int b0 = blockIdx.y * 32;
  int to = tid & 15, tb = tid >> 4;
  float acc[2][2] = {};

  for (int kc = 0; kc < 64; ++kc) {
    __syncthreads();
    {  // stage spikes tile -> [k][b]
      int kk = tid & 31, r8 = tid >> 5;
#pragma unroll
      for (int rr = 0; rr < 32; rr += 8)
        At[kk * 34 + r8 + rr] =
            spikes[(size_t)(b0 + r8 + rr) * HID + kc * 32 + kk];
    }
    {  // stage WoutT tile -> [k][o]
      int oo = tid & 31, kr = tid >> 5;
#pragma unroll
      for (int rr = 0; rr < 32; rr += 8)
        Bt[(kr + rr) * 32 + oo] =
            WoutT[(size_t)(kc * 32 + kr + rr) * OUT_SZ + o0 + oo];
    }
    __syncthreads();
#pragma unroll
    for (int k2 = 0; k2 < 32; ++k2) {
      float a_[2], w_[2];
      *(float2*)a_ = *(const float2*)&At[k2 * 34 + tb * 2];
      *(float2*)w_ = *(const float2*)&Bt[k2 * 32 + to * 2];
      acc[0][0] = fmaf(a_[0], w_[0], acc[0][0]);
      acc[0][1] = fmaf(a_[0], w_[1], acc[0][1]);
      acc[1][0] = fmaf(a_[1], w_[0], acc[1][0]);
      acc[1][1] = fmaf(a_[1], w_[1], acc[1][1]);
    }
  }

#pragma unroll
  for (int i = 0; i < 2; ++i) {
    int b = b0 + tb * 2 + i;
#pragma unroll
    for (int jj = 0; jj < 2; ++jj) {
      int o = o0 + to * 2 + jj;
      float out = acc[i][jj] + b_out[o];
      float inc = (out > 0.0f) ? 1.0f : 0.0f;
      int idx = b * OUT_SZ + o;
      float prev = (t == 0) ? 0.0f : s[idx];
      s[idx] = prev + inc;
    }
  }
}

// ---------------------------------------------------------------------------
extern "C" void kernel_launch(void* const* d_in, const int* in_sizes, int n_in,
                              void* d_out, int out_size, void* d_ws, size_t ws_size,
                              hipStream_t stream) {
  const float* x    = (const float*)d_in[0];
  const float* Win  = (const float*)d_in[1];
  const float* Wout = (const float*)d_in[2];
  const float* bout = (const float*)d_in[3];
  float* s = (float*)d_out;

  char* ws = (char*)d_ws;
  const size_t OFF_WINT  = 0;                       // 3072*2048*4 = 25165824
  const size_t OFF_WOUTT = 25165824;                // 2048*512*4  = 4194304
  const size_t OFF_BITS  = 29360128;                // 10*512*96*4 = 1966080
  const size_t OFF_V     = 31326208;                // 512*2048*4  = 4194304
  const size_t OFF_SPK   = 35520512;                // 512*2048*4  = 4194304
  float*    WinT     = (float*)(ws + OFF_WINT);
  float*    WoutT    = (float*)(ws + OFF_WOUTT);
  uint32_t* pre_bits = (uint32_t*)(ws + OFF_BITS);
  float*    v        = (float*)(ws + OFF_V);
  float*    spikes   = (float*)(ws + OFF_SPK);

  // Host-side derivation of the 10 step keys (partitionable fold-like split):
  // key_t = threefry((0,42), (0,t))
  Keys hk;
  for (int t = 0; t < T_STEPS; ++t) {
    uint32_t y0, y1;
    threefry2x32(0u, 42u, 0u, (uint32_t)t, y0, y1);
    hk.k[2*t]   = y0;
    hk.k[2*t+1] = y1;
  }

  dim3 blkT(32, 8);
  hipLaunchKernelGGL(transpose_kernel, dim3(IN_SZ/32, HID/32), blkT, 0, stream,
                     Win, WinT, HID, IN_SZ);
  hipLaunchKernelGGL(transpose_kernel, dim3(HID/32, OUT_SZ/32), blkT, 0, stream,
                     Wout, WoutT, OUT_SZ, HID);
  hipLaunchKernelGGL(spikegen_kernel, dim3(NELEM/256), dim3(256), 0, stream,
                     x, pre_bits, hk);

  for (int t = 0; t < T_STEPS; ++t) {
    hipLaunchKernelGGL(hidden_kernel, dim3(HID/64, B_SZ/64), dim3(256), 0,
                       stream, WinT, pre_bits, v, spikes, t);
    hipLaunchKernelGGL(out_kernel, dim3(OUT_SZ/32, B_SZ/32), dim3(256), 0,
                       stream, WoutT, spikes, bout, s, t);
  }
}

// Round 3
// 568.645 us; speedup vs baseline: 4.0493x; 4.0493x over previous
//
#include <hip/hip_runtime.h>
#include <cstdint>

#define B_SZ   512
#define IN_SZ  3072
#define HID    2048
#define OUT_SZ 512
#define T_STEPS 10
#define NELEM  (512u*3072u)
#define KW     96                    // in_bits words per row
#define BITS_T_STRIDE (512u*96u)

typedef __attribute__((ext_vector_type(8))) short short8v;   // 8 bf16
typedef __attribute__((ext_vector_type(4))) float f32x4;
typedef __attribute__((ext_vector_type(4))) unsigned int u32x4;

struct Keys { uint32_t k[2*T_STEPS]; };

__host__ __device__ inline void threefry2x32(uint32_t k0, uint32_t k1,
                                             uint32_t x0, uint32_t x1,
                                             uint32_t& y0, uint32_t& y1) {
  const uint32_t ks2 = k0 ^ k1 ^ 0x1BD11BDAu;
#define TF_R(r) { x0 += x1; x1 = (x1 << (r)) | (x1 >> (32-(r))); x1 ^= x0; }
  x0 += k0; x1 += k1;
  TF_R(13) TF_R(15) TF_R(26) TF_R(6)   x0 += k1;  x1 += ks2 + 1u;
  TF_R(17) TF_R(29) TF_R(16) TF_R(24)  x0 += ks2; x1 += k0  + 2u;
  TF_R(13) TF_R(15) TF_R(26) TF_R(6)   x0 += k0;  x1 += k1  + 3u;
  TF_R(17) TF_R(29) TF_R(16) TF_R(24)  x0 += k1;  x1 += ks2 + 4u;
  TF_R(13) TF_R(15) TF_R(26) TF_R(6)   x0 += ks2; x1 += k0  + 5u;
#undef TF_R
  y0 = x0; y1 = x1;
}

// ---------------- spike generation (verified round 1) ----------------------
__global__ __launch_bounds__(256) void spikegen_kernel(
    const float* __restrict__ x, uint32_t* __restrict__ pre_bits, Keys keys) {
  uint32_t m = blockIdx.x * 256u + threadIdx.x;
  uint32_t b = m / IN_SZ;
  uint32_t j = m - b * IN_SZ;
  float xv = x[m];
  float p = (float)(1.0 / (1.0 + exp(-(double)xv)));
  uint32_t lane = threadIdx.x & 63u;
  uint32_t wbase = b * KW + (j >> 5);
#pragma unroll
  for (int t = 0; t < T_STEPS; ++t) {
    uint32_t y0, y1;
    threefry2x32(keys.k[2*t], keys.k[2*t+1], 0u, m, y0, y1);
    uint32_t bits = y0 ^ y1;
    float u = __uint_as_float((bits >> 9) | 0x3f800000u) - 1.0f;
    unsigned long long mask = __ballot(u < p);
    if (lane == 0u) {
      *reinterpret_cast<unsigned long long*>(
          &pre_bits[(uint32_t)t * BITS_T_STRIDE + wbase]) = mask;
    }
  }
}

// ---------------- exact 3-way bf16 split of f32 weights --------------------
__device__ __forceinline__ ushort rne_bf16(float f) {
  uint32_t u = __float_as_uint(f);
  return (ushort)((u + 0x7FFFu + ((u >> 16) & 1u)) >> 16);
}

__global__ __launch_bounds__(256) void split_kernel(
    const float* __restrict__ W, ushort* __restrict__ hi,
    ushort* __restrict__ mid, ushort* __restrict__ lo) {
  uint32_t i = blockIdx.x * 256u + threadIdx.x;
  float w = W[i];
  ushort h = rne_bf16(w);
  float hf = __uint_as_float((uint32_t)h << 16);
  float r1 = w - hf;                       // exact
  ushort m = rne_bf16(r1);
  float mf = __uint_as_float((uint32_t)m << 16);
  float r2 = r1 - mf;                      // exact
  ushort l = rne_bf16(r2);                 // exact (<=8 significant bits left)
  hi[i] = h; mid[i] = m; lo[i] = l;
}

// ---------------- bit byte -> 8 bf16 {0,1} ---------------------------------
__device__ __forceinline__ short8v expand8(uint32_t b) {
  union { uint32_t u[4]; short8v v; } r;
#pragma unroll
  for (int j = 0; j < 4; ++j) {
    uint32_t x = b >> (2*j);
    r.u[j] = ((x & 1u) | ((x & 2u) << 15)) * 0x3F80u;  // bf16 1.0 per set bit
  }
  return r.v;
}

#define MFMA(a, b, c) __builtin_amdgcn_mfma_f32_16x16x32_bf16((a), (b), (c), 0, 0, 0)

// ---------------- hidden layer, all 10 steps fused, v in registers ---------
__global__ __launch_bounds__(256) void hidden_mfma(
    const ushort* __restrict__ Whi, const ushort* __restrict__ Wmid,
    const ushort* __restrict__ Wlo,
    const uint32_t* __restrict__ in_bits,   // [T][512][96]
    uint8_t* __restrict__ spk) {            // [T][512][256] bit-packed along n
  int tid  = threadIdx.x;
  int wave = tid >> 6, lane = tid & 63;
  int col  = lane & 15, kb = lane >> 4;
  int n0 = blockIdx.x * 64 + wave * 16;     // this wave's 16 hidden cols
  int m0 = blockIdx.y * 64;                 // block's 64 batch rows
  const ushort* bh = Whi  + (size_t)(n0 + col) * IN_SZ;
  const ushort* bm = Wmid + (size_t)(n0 + col) * IN_SZ;
  const ushort* bl = Wlo  + (size_t)(n0 + col) * IN_SZ;

  f32x4 vst[4] = {{0.f,0.f,0.f,0.f},{0.f,0.f,0.f,0.f},
                  {0.f,0.f,0.f,0.f},{0.f,0.f,0.f,0.f}};

  for (int t = 0; t < T_STEPS; ++t) {
    const uint32_t* bt = in_bits + (size_t)t * BITS_T_STRIDE;
    f32x4 acc[4] = {{0.f,0.f,0.f,0.f},{0.f,0.f,0.f,0.f},
                    {0.f,0.f,0.f,0.f},{0.f,0.f,0.f,0.f}};
    for (int kc4 = 0; kc4 < 24; ++kc4) {
      u32x4 aw[4];
#pragma unroll
      for (int f = 0; f < 4; ++f)
        aw[f] = *(const u32x4*)&bt[(size_t)(m0 + f*16 + col) * KW + kc4*4];
#pragma unroll
      for (int s = 0; s < 4; ++s) {
        int k = (kc4*4 + s) * 32 + kb * 8;
        short8v B0 = *(const short8v*)&bh[k];
        short8v B1 = *(const short8v*)&bm[k];
        short8v B2 = *(const short8v*)&bl[k];
        short8v A[4];
#pragma unroll
        for (int f = 0; f < 4; ++f)
          A[f] = expand8((aw[f][s] >> (kb*8)) & 0xFFu);
#pragma unroll
        for (int f = 0; f < 4; ++f) acc[f] = MFMA(A[f], B0, acc[f]);
#pragma unroll
        for (int f = 0; f < 4; ++f) acc[f] = MFMA(A[f], B1, acc[f]);
#pragma unroll
        for (int f = 0; f < 4; ++f) acc[f] = MFMA(A[f], B2, acc[f]);
      }
    }
    // LIF update + spike-bit emission (pragma must open a compound stmt)
    {
#pragma clang fp contract(off)
#pragma unroll
      for (int f = 0; f < 4; ++f) {
#pragma unroll
        for (int r = 0; r < 4; ++r) {
          float vd = vst[f][r] * 0.3f;
          float vn = vd + acc[f][r];
          bool fire = (vn >= 1.0f);
          vst[f][r] = fire ? 0.0f : vn;
          unsigned long long mask = __ballot(fire);
          if (col == 0) {
            int m = m0 + f*16 + kb*4 + r;
            *(ushort*)&spk[(size_t)t * (512*256) + (size_t)m * 256 + (n0 >> 3)] =
                (ushort)((mask >> (16*kb)) & 0xFFFFu);
          }
        }
      }
    }
  }
}

// ---------------- output layer: one block per (n-tile, m-tile, t) ----------
__global__ __launch_bounds__(256) void out_mfma(
    const ushort* __restrict__ Ohi, const ushort* __restrict__ Omid,
    const ushort* __restrict__ Olo,
    const uint8_t* __restrict__ spk,        // [T][512][256]
    const float* __restrict__ bout,
    float* __restrict__ s) {                // [512][512], pre-zeroed
  int t   = blockIdx.z;
  int tid = threadIdx.x;
  int wave = tid >> 6, lane = tid & 63;
  int col  = lane & 15, kb = lane >> 4;
  int n0 = blockIdx.x * 64 + wave * 16;
  int m0 = blockIdx.y * 64;
  const ushort* bh = Ohi  + (size_t)(n0 + col) * HID;
  const ushort* bm = Omid + (size_t)(n0 + col) * HID;
  const ushort* bl = Olo  + (size_t)(n0 + col) * HID;
  const uint8_t* st = spk + (size_t)t * (512*256);

  f32x4 acc[4] = {{0.f,0.f,0.f,0.f},{0.f,0.f,0.f,0.f},
                  {0.f,0.f,0.f,0.f},{0.f,0.f,0.f,0.f}};
  for (int kc4 = 0; kc4 < 16; ++kc4) {      // K = 2048 = 16 * 4 * 32
    u32x4 aw[4];
#pragma unroll
    for (int f = 0; f < 4; ++f)
      aw[f] = *(const u32x4*)&st[(size_t)(m0 + f*16 + col) * 256 + kc4*16];
#pragma unroll
    for (int sv = 0; sv < 4; ++sv) {
      int k = (kc4*4 + sv) * 32 + kb * 8;
      short8v B0 = *(const short8v*)&bh[k];
      short8v B1 = *(const short8v*)&bm[k];
      short8v B2 = *(const short8v*)&bl[k];
      short8v A[4];
#pragma unroll
      for (int f = 0; f < 4; ++f)
        A[f] = expand8((aw[f][sv] >> (kb*8)) & 0xFFu);
#pragma unroll
      for (int f = 0; f < 4; ++f) acc[f] = MFMA(A[f], B0, acc[f]);
#pragma unroll
      for (int f = 0; f < 4; ++f) acc[f] = MFMA(A[f], B1, acc[f]);
#pragma unroll
      for (int f = 0; f < 4; ++f) acc[f] = MFMA(A[f], B2, acc[f]);
    }
  }
  float bo = bout[n0 + col];
#pragma unroll
  for (int f = 0; f < 4; ++f) {
#pragma unroll
    for (int r = 0; r < 4; ++r) {
      float out = acc[f][r] + bo;
      if (out > 0.0f) {
        int b = m0 + f*16 + kb*4 + r;
        atomicAdd(&s[(size_t)b * OUT_SZ + (n0 + col)], 1.0f);
      }
    }
  }
}

// ---------------------------------------------------------------------------
extern "C" void kernel_launch(void* const* d_in, const int* in_sizes, int n_in,
                              void* d_out, int out_size, void* d_ws, size_t ws_size,
                              hipStream_t stream) {
  const float* x    = (const float*)d_in[0];
  const float* Win  = (const float*)d_in[1];   // [2048][3072]
  const float* Wout = (const float*)d_in[2];   // [512][2048]
  const float* bout = (const float*)d_in[3];
  float* s = (float*)d_out;                    // [512][512]

  char* ws = (char*)d_ws;
  // bf16 splits of Win: 3 x 2048*3072*2 B
  ushort* Whi  = (ushort*)(ws + 0);
  ushort* Wmid = (ushort*)(ws + 12582912);
  ushort* Wlo  = (ushort*)(ws + 25165824);
  // bf16 splits of Wout: 3 x 512*2048*2 B
  ushort* Ohi  = (ushort*)(ws + 37748736);
  ushort* Omid = (ushort*)(ws + 39845888);
  ushort* Olo  = (ushort*)(ws + 41943040);
  uint32_t* in_bits = (uint32_t*)(ws + 44040192);  // 10*512*96*4 = 1966080
  uint8_t*  spk     = (uint8_t*)(ws + 46006272);   // 10*512*256  = 1310720

  Keys hk;
  for (int t = 0; t < T_STEPS; ++t) {
    uint32_t y0, y1;
    threefry2x32(0u, 42u, 0u, (uint32_t)t, y0, y1);
    hk.k[2*t] = y0; hk.k[2*t+1] = y1;
  }

  (void)hipMemsetAsync(d_out, 0, (size_t)OUT_SZ * B_SZ * sizeof(float), stream);
  hipLaunchKernelGGL(split_kernel, dim3((HID*IN_SZ)/256), dim3(256), 0, stream,
                     Win, Whi, Wmid, Wlo);
  hipLaunchKernelGGL(split_kernel, dim3((OUT_SZ*HID)/256), dim3(256), 0, stream,
                     Wout, Ohi, Omid, Olo);
  hipLaunchKernelGGL(spikegen_kernel, dim3(NELEM/256), dim3(256), 0, stream,
                     x, in_bits, hk);
  hipLaunchKernelGGL(hidden_mfma, dim3(HID/64, B_SZ/64), dim3(256), 0, stream,
                     Whi, Wmid, Wlo, in_bits, spk);
  hipLaunchKernelGGL(out_mfma, dim3(OUT_SZ/64, B_SZ/64, T_STEPS), dim3(256), 0,
                     stream, Ohi, Omid, Olo, spk, bout, s);
}

// Round 4
// 562.839 us; speedup vs baseline: 4.0910x; 1.0103x over previous
//
#include <hip/hip_runtime.h>
#include <cstdint>

#define B_SZ   512
#define IN_SZ  3072
#define HID    2048
#define OUT_SZ 512
#define T_STEPS 10
#define NELEM  (512u*3072u)
#define KW     96                    // in_bits words per row
#define BITS_T_STRIDE (512u*96u)
#define M_ALL  (T_STEPS * B_SZ)      // 5120 rows in the de-fused hidden GEMM

typedef __attribute__((ext_vector_type(8))) short short8v;   // 8 bf16
typedef __attribute__((ext_vector_type(4))) float f32x4;
typedef __attribute__((ext_vector_type(4))) unsigned int u32x4;

struct Keys { uint32_t k[2*T_STEPS]; };

__host__ __device__ inline void threefry2x32(uint32_t k0, uint32_t k1,
                                             uint32_t x0, uint32_t x1,
                                             uint32_t& y0, uint32_t& y1) {
  const uint32_t ks2 = k0 ^ k1 ^ 0x1BD11BDAu;
#define TF_R(r) { x0 += x1; x1 = (x1 << (r)) | (x1 >> (32-(r))); x1 ^= x0; }
  x0 += k0; x1 += k1;
  TF_R(13) TF_R(15) TF_R(26) TF_R(6)   x0 += k1;  x1 += ks2 + 1u;
  TF_R(17) TF_R(29) TF_R(16) TF_R(24)  x0 += ks2; x1 += k0  + 2u;
  TF_R(13) TF_R(15) TF_R(26) TF_R(6)   x0 += k0;  x1 += k1  + 3u;
  TF_R(17) TF_R(29) TF_R(16) TF_R(24)  x0 += k1;  x1 += ks2 + 4u;
  TF_R(13) TF_R(15) TF_R(26) TF_R(6)   x0 += ks2; x1 += k0  + 5u;
#undef TF_R
  y0 = x0; y1 = x1;
}

// ---------------- spike generation (verified rounds 1/3) -------------------
__global__ __launch_bounds__(256) void spikegen_kernel(
    const float* __restrict__ x, uint32_t* __restrict__ pre_bits, Keys keys) {
  uint32_t m = blockIdx.x * 256u + threadIdx.x;
  uint32_t b = m / IN_SZ;
  uint32_t j = m - b * IN_SZ;
  float xv = x[m];
  float p = (float)(1.0 / (1.0 + exp(-(double)xv)));
  uint32_t lane = threadIdx.x & 63u;
  uint32_t wbase = b * KW + (j >> 5);
#pragma unroll
  for (int t = 0; t < T_STEPS; ++t) {
    uint32_t y0, y1;
    threefry2x32(keys.k[2*t], keys.k[2*t+1], 0u, m, y0, y1);
    uint32_t bits = y0 ^ y1;
    float u = __uint_as_float((bits >> 9) | 0x3f800000u) - 1.0f;
    unsigned long long mask = __ballot(u < p);
    if (lane == 0u) {
      *reinterpret_cast<unsigned long long*>(
          &pre_bits[(uint32_t)t * BITS_T_STRIDE + wbase]) = mask;
    }
  }
}

// ---------------- exact 3-way bf16 split of f32 weights --------------------
__device__ __forceinline__ ushort rne_bf16(float f) {
  uint32_t u = __float_as_uint(f);
  return (ushort)((u + 0x7FFFu + ((u >> 16) & 1u)) >> 16);
}

__global__ __launch_bounds__(256) void split_kernel(
    const float* __restrict__ W, ushort* __restrict__ hi,
    ushort* __restrict__ mid, ushort* __restrict__ lo) {
  uint32_t i = blockIdx.x * 256u + threadIdx.x;
  float w = W[i];
  ushort h = rne_bf16(w);
  float hf = __uint_as_float((uint32_t)h << 16);
  float r1 = w - hf;                       // exact
  ushort m = rne_bf16(r1);
  float mf = __uint_as_float((uint32_t)m << 16);
  float r2 = r1 - mf;                      // exact
  ushort l = rne_bf16(r2);                 // exact (<=8 significant bits left)
  hi[i] = h; mid[i] = m; lo[i] = l;
}

// ---------------- bit byte -> 8 bf16 {0,1} ---------------------------------
__device__ __forceinline__ short8v expand8(uint32_t b) {
  union { uint32_t u[4]; short8v v; } r;
#pragma unroll
  for (int j = 0; j < 4; ++j) {
    uint32_t x = b >> (2*j);
    r.u[j] = ((x & 1u) | ((x & 2u) << 15)) * 0x3F80u;  // bf16 1.0 per set bit
  }
  return r.v;
}

#define MFMA(a, b, c) __builtin_amdgcn_mfma_f32_16x16x32_bf16((a), (b), (c), 0, 0, 0)

// ---------------- hidden GEMM, de-fused over t: H = pre @ Win^T ------------
// A rows = t*512 + b (5120 total). LDS-staged cooperative A expansion.
#define ALD 72   // A_lds row stride in bf16 (144 B: 16B-aligned, 8 bank starts)
__global__ __launch_bounds__(256) void gemm_hidden(
    const ushort* __restrict__ Whi, const ushort* __restrict__ Wmid,
    const ushort* __restrict__ Wlo,
    const uint32_t* __restrict__ in_bits,   // [5120][96]
    float* __restrict__ H) {                // [5120][2048]
  __shared__ ushort A_lds[2][64 * ALD];
  int tid  = threadIdx.x;
  int wave = tid >> 6, lane = tid & 63;
  int col  = lane & 15, kb = lane >> 4;
  int n0 = blockIdx.x * 64 + wave * 16;
  int m0 = blockIdx.y * 64;
  const ushort* bh = Whi  + (size_t)(n0 + col) * IN_SZ;
  const ushort* bm = Wmid + (size_t)(n0 + col) * IN_SZ;
  const ushort* bl = Wlo  + (size_t)(n0 + col) * IN_SZ;

  // staging role: thread handles row sm, 16 k-bits at offset 16*q of each chunk
  int sm = tid & 63, q = tid >> 6;
  const uint32_t* brow = in_bits + (size_t)(m0 + sm) * KW + (q >> 1);
  int swoff = sm * ALD + q * 16;
  int shq = 16 * (q & 1);

  f32x4 acc[4] = {{0.f,0.f,0.f,0.f},{0.f,0.f,0.f,0.f},
                  {0.f,0.f,0.f,0.f},{0.f,0.f,0.f,0.f}};

  {  // stage chunk 0
    uint32_t b16 = (brow[0] >> shq) & 0xFFFFu;
    *(short8v*)&A_lds[0][swoff]     = expand8(b16 & 0xFFu);
    *(short8v*)&A_lds[0][swoff + 8] = expand8(b16 >> 8);
  }
  __syncthreads();

  for (int kc = 0; kc < 48; ++kc) {   // 64 k per chunk
    int cur = kc & 1;
    if (kc + 1 < 48) {                // stage next chunk into the other buffer
      uint32_t b16 = (brow[(kc + 1) * 2] >> shq) & 0xFFFFu;
      *(short8v*)&A_lds[cur ^ 1][swoff]     = expand8(b16 & 0xFFu);
      *(short8v*)&A_lds[cur ^ 1][swoff + 8] = expand8(b16 >> 8);
    }
#pragma unroll
    for (int s = 0; s < 2; ++s) {
      int k = kc * 64 + s * 32 + kb * 8;
      short8v B0 = *(const short8v*)&bh[k];
      short8v B1 = *(const short8v*)&bm[k];
      short8v B2 = *(const short8v*)&bl[k];
      short8v A[4];
#pragma unroll
      for (int f = 0; f < 4; ++f)
        A[f] = *(const short8v*)&A_lds[cur][(f*16 + col) * ALD + s*32 + kb*8];
#pragma unroll
      for (int f = 0; f < 4; ++f) acc[f] = MFMA(A[f], B0, acc[f]);
#pragma unroll
      for (int f = 0; f < 4; ++f) acc[f] = MFMA(A[f], B1, acc[f]);
#pragma unroll
      for (int f = 0; f < 4; ++f) acc[f] = MFMA(A[f], B2, acc[f]);
    }
    __syncthreads();
  }

#pragma unroll
  for (int f = 0; f < 4; ++f)
#pragma unroll
    for (int r = 0; r < 4; ++r) {
      int m = m0 + f*16 + kb*4 + r;
      H[(size_t)m * HID + n0 + col] = acc[f][r];
    }
}

// ---------------- LIF scan over t (the only sequential part) ---------------
__global__ __launch_bounds__(256) void lif_scan(
    const float* __restrict__ H,           // [5120][2048]
    uint8_t* __restrict__ spk) {           // [T][512][256] bit-packed along n
  int idx  = blockIdx.x * 256 + threadIdx.x;   // 0 .. 512*2048-1
  int b = idx >> 11, n = idx & 2047;
  int lane = threadIdx.x & 63;
  size_t spk_off = (size_t)b * 256 + (size_t)((n >> 3) & ~7);
  float v = 0.f;
#pragma unroll
  for (int t = 0; t < T_STEPS; ++t) {
    float h = H[(size_t)(t * B_SZ + b) * HID + n];
    bool fire;
    {
#pragma clang fp contract(off)
      float vd = v * 0.3f;
      float vn = vd + h;
      fire = (vn >= 1.0f);
      v = fire ? 0.0f : vn;
    }
    unsigned long long mask = __ballot(fire);
    if (lane == 0)
      *(unsigned long long*)&spk[(size_t)t * (512*256) + spk_off] = mask;
  }
}

// ---------------- output layer: one block per (n-tile, m-tile, t) ----------
__global__ __launch_bounds__(256) void out_mfma(
    const ushort* __restrict__ Ohi, const ushort* __restrict__ Omid,
    const ushort* __restrict__ Olo,
    const uint8_t* __restrict__ spk,        // [T][512][256]
    const float* __restrict__ bout,
    float* __restrict__ s) {                // [512][512], pre-zeroed
  int t   = blockIdx.z;
  int tid = threadIdx.x;
  int wave = tid >> 6, lane = tid & 63;
  int col  = lane & 15, kb = lane >> 4;
  int n0 = blockIdx.x * 64 + wave * 16;
  int m0 = blockIdx.y * 64;
  const ushort* bh = Ohi  + (size_t)(n0 + col) * HID;
  const ushort* bm = Omid + (size_t)(n0 + col) * HID;
  const ushort* bl = Olo  + (size_t)(n0 + col) * HID;
  const uint8_t* st = spk + (size_t)t * (512*256);

  f32x4 acc[4] = {{0.f,0.f,0.f,0.f},{0.f,0.f,0.f,0.f},
                  {0.f,0.f,0.f,0.f},{0.f,0.f,0.f,0.f}};
  for (int kc4 = 0; kc4 < 16; ++kc4) {      // K = 2048 = 16 * 4 * 32
    u32x4 aw[4];
#pragma unroll
    for (int f = 0; f < 4; ++f)
      aw[f] = *(const u32x4*)&st[(size_t)(m0 + f*16 + col) * 256 + kc4*16];
#pragma unroll
    for (int sv = 0; sv < 4; ++sv) {
      int k = (kc4*4 + sv) * 32 + kb * 8;
      short8v B0 = *(const short8v*)&bh[k];
      short8v B1 = *(const short8v*)&bm[k];
      short8v B2 = *(const short8v*)&bl[k];
      short8v A[4];
#pragma unroll
      for (int f = 0; f < 4; ++f)
        A[f] = expand8((aw[f][sv] >> (kb*8)) & 0xFFu);
#pragma unroll
      for (int f = 0; f < 4; ++f) acc[f] = MFMA(A[f], B0, acc[f]);
#pragma unroll
      for (int f = 0; f < 4; ++f) acc[f] = MFMA(A[f], B1, acc[f]);
#pragma unroll
      for (int f = 0; f < 4; ++f) acc[f] = MFMA(A[f], B2, acc[f]);
    }
  }
  float bo = bout[n0 + col];
#pragma unroll
  for (int f = 0; f < 4; ++f) {
#pragma unroll
    for (int r = 0; r < 4; ++r) {
      float out = acc[f][r] + bo;
      if (out > 0.0f) {
        int b = m0 + f*16 + kb*4 + r;
        atomicAdd(&s[(size_t)b * OUT_SZ + (n0 + col)], 1.0f);
      }
    }
  }
}

// ---------------------------------------------------------------------------
extern "C" void kernel_launch(void* const* d_in, const int* in_sizes, int n_in,
                              void* d_out, int out_size, void* d_ws, size_t ws_size,
                              hipStream_t stream) {
  const float* x    = (const float*)d_in[0];
  const float* Win  = (const float*)d_in[1];   // [2048][3072]
  const float* Wout = (const float*)d_in[2];   // [512][2048]
  const float* bout = (const float*)d_in[3];
  float* s = (float*)d_out;                    // [512][512]

  char* ws = (char*)d_ws;
  ushort* Whi  = (ushort*)(ws + 0);            // 3 x 12582912
  ushort* Wmid = (ushort*)(ws + 12582912);
  ushort* Wlo  = (ushort*)(ws + 25165824);
  ushort* Ohi  = (ushort*)(ws + 37748736);     // 3 x 2097152
  ushort* Omid = (ushort*)(ws + 39845888);
  ushort* Olo  = (ushort*)(ws + 41943040);
  uint32_t* in_bits = (uint32_t*)(ws + 44040192);  // 10*512*96*4 = 1966080
  uint8_t*  spk     = (uint8_t*)(ws + 46006272);   // 10*512*256  = 1310720
  float*    H       = (float*)(ws + 47316992);     // 5120*2048*4 = 41943040

  Keys hk;
  for (int t = 0; t < T_STEPS; ++t) {
    uint32_t y0, y1;
    threefry2x32(0u, 42u, 0u, (uint32_t)t, y0, y1);
    hk.k[2*t] = y0; hk.k[2*t+1] = y1;
  }

  (void)hipMemsetAsync(d_out, 0, (size_t)OUT_SZ * B_SZ * sizeof(float), stream);
  hipLaunchKernelGGL(split_kernel, dim3((HID*IN_SZ)/256), dim3(256), 0, stream,
                     Win, Whi, Wmid, Wlo);
  hipLaunchKernelGGL(split_kernel, dim3((OUT_SZ*HID)/256), dim3(256), 0, stream,
                     Wout, Ohi, Omid, Olo);
  hipLaunchKernelGGL(spikegen_kernel, dim3(NELEM/256), dim3(256), 0, stream,
                     x, in_bits, hk);
  hipLaunchKernelGGL(gemm_hidden, dim3(HID/64, M_ALL/64), dim3(256), 0, stream,
                     Whi, Wmid, Wlo, in_bits, H);
  hipLaunchKernelGGL(lif_scan, dim3((B_SZ*HID)/256), dim3(256), 0, stream,
                     H, spk);
  hipLaunchKernelGGL(out_mfma, dim3(OUT_SZ/64, B_SZ/64, T_STEPS), dim3(256), 0,
                     stream, Ohi, Omid, Olo, spk, bout, s);
}

// Round 5
// 282.820 us; speedup vs baseline: 8.1416x; 1.9901x over previous
//
#include <hip/hip_runtime.h>
#include <cstdint>

#define B_SZ   512
#define IN_SZ  3072
#define HID    2048
#define OUT_SZ 512
#define T_STEPS 10
#define NELEM  (512u*3072u)
#define KW     96                    // in_bits words per row
#define BITS_T_STRIDE (512u*96u)
#define M_ALL  (T_STEPS * B_SZ)      // 5120 rows in the de-fused hidden GEMM

typedef __attribute__((ext_vector_type(8))) short short8v;   // 8 bf16
typedef __attribute__((ext_vector_type(4))) float f32x4;
typedef __attribute__((ext_vector_type(4))) unsigned int u32x4;

struct Keys { uint32_t k[2*T_STEPS]; };

__host__ __device__ inline void threefry2x32(uint32_t k0, uint32_t k1,
                                             uint32_t x0, uint32_t x1,
                                             uint32_t& y0, uint32_t& y1) {
  const uint32_t ks2 = k0 ^ k1 ^ 0x1BD11BDAu;
#define TF_R(r) { x0 += x1; x1 = (x1 << (r)) | (x1 >> (32-(r))); x1 ^= x0; }
  x0 += k0; x1 += k1;
  TF_R(13) TF_R(15) TF_R(26) TF_R(6)   x0 += k1;  x1 += ks2 + 1u;
  TF_R(17) TF_R(29) TF_R(16) TF_R(24)  x0 += ks2; x1 += k0  + 2u;
  TF_R(13) TF_R(15) TF_R(26) TF_R(6)   x0 += k0;  x1 += k1  + 3u;
  TF_R(17) TF_R(29) TF_R(16) TF_R(24)  x0 += k1;  x1 += ks2 + 4u;
  TF_R(13) TF_R(15) TF_R(26) TF_R(6)   x0 += ks2; x1 += k0  + 5u;
#undef TF_R
  y0 = x0; y1 = x1;
}

// ---------------- spike generation (verified rounds 1/3/4) -----------------
__global__ __launch_bounds__(256) void spikegen_kernel(
    const float* __restrict__ x, uint32_t* __restrict__ pre_bits, Keys keys) {
  uint32_t m = blockIdx.x * 256u + threadIdx.x;
  uint32_t b = m / IN_SZ;
  uint32_t j = m - b * IN_SZ;
  float xv = x[m];
  float p = (float)(1.0 / (1.0 + exp(-(double)xv)));
  uint32_t lane = threadIdx.x & 63u;
  uint32_t wbase = b * KW + (j >> 5);
#pragma unroll
  for (int t = 0; t < T_STEPS; ++t) {
    uint32_t y0, y1;
    threefry2x32(keys.k[2*t], keys.k[2*t+1], 0u, m, y0, y1);
    uint32_t bits = y0 ^ y1;
    float u = __uint_as_float((bits >> 9) | 0x3f800000u) - 1.0f;
    unsigned long long mask = __ballot(u < p);
    if (lane == 0u) {
      *reinterpret_cast<unsigned long long*>(
          &pre_bits[(uint32_t)t * BITS_T_STRIDE + wbase]) = mask;
    }
  }
}

// ---------------- exact 3-way bf16 split, FRAGMENT-ordered output ----------
// layout: idx = ((nt*(K/32) + ks)*64 + kb*16 + col)*8 + e
//   for W[n][k]: nt=n>>4, col=n&15, ks=k>>5, kb=(k>>3)&3, e=k&7
// so a wave (lane = kb*16+col) loads one 1KB-contiguous fragment per ks.
__device__ __forceinline__ ushort rne_bf16(float f) {
  uint32_t u = __float_as_uint(f);
  return (ushort)((u + 0x7FFFu + ((u >> 16) & 1u)) >> 16);
}

__global__ __launch_bounds__(256) void split_frag(
    const float* __restrict__ W, ushort* __restrict__ hi,
    ushort* __restrict__ mid, ushort* __restrict__ lo, int K) {
  int k = blockIdx.x * 256 + threadIdx.x;
  int n = blockIdx.y;
  float w = W[(size_t)n * K + k];
  ushort h = rne_bf16(w);
  float hf = __uint_as_float((uint32_t)h << 16);
  float r1 = w - hf;                       // exact
  ushort m = rne_bf16(r1);
  float mf = __uint_as_float((uint32_t)m << 16);
  float r2 = r1 - mf;                      // exact
  ushort l = rne_bf16(r2);                 // exact
  int nt = n >> 4, c = n & 15, ks = k >> 5, kb = (k >> 3) & 3, e = k & 7;
  size_t idx = (((size_t)nt * (K / 32) + ks) * 64 + kb * 16 + c) * 8 + e;
  hi[idx] = h; mid[idx] = m; lo[idx] = l;
}

// ---------------- bit byte -> 8 bf16 {0,1} ---------------------------------
__device__ __forceinline__ short8v expand8(uint32_t b) {
  union { uint32_t u[4]; short8v v; } r;
#pragma unroll
  for (int j = 0; j < 4; ++j) {
    uint32_t x = b >> (2*j);
    r.u[j] = ((x & 1u) | ((x & 2u) << 15)) * 0x3F80u;  // bf16 1.0 per set bit
  }
  return r.v;
}

#define MFMA(a, b, c) __builtin_amdgcn_mfma_f32_16x16x32_bf16((a), (b), (c), 0, 0, 0)

// ---------------- hidden GEMM: H = pre @ Win^T, BM=128, frag-ordered -------
// grid (HID/64=32, M_ALL/128=40); 4 waves, wave owns 16 n-cols x 128 m-rows.
// A tile in LDS, fragment-ordered: [buf][ (slot*8+f)*64 + lane ]*8, slot=s
__global__ __launch_bounds__(256) void gemm_hidden(
    const ushort* __restrict__ Whi, const ushort* __restrict__ Wmid,
    const ushort* __restrict__ Wlo,
    const uint32_t* __restrict__ in_bits,   // [5120][96]
    float* __restrict__ H) {                // [5120][2048]
  __shared__ ushort A_lds[2][2 * 8 * 64 * 8];   // 2 buf x 8192 ushort = 32 KB
  int tid  = threadIdx.x;
  int wave = tid >> 6, lane = tid & 63;
  int col  = lane & 15, kb = lane >> 4;
  int nt = blockIdx.x * 4 + wave;
  int m0 = blockIdx.y * 128;
  const ushort* bh = Whi  + (size_t)nt * (IN_SZ/32) * 512;
  const ushort* bm = Wmid + (size_t)nt * (IN_SZ/32) * 512;
  const ushort* bl = Wlo  + (size_t)nt * (IN_SZ/32) * 512;

  // staging role: thread = (half h, row sm); expands one 32-bit word per kc
  int sm = tid & 127, h = tid >> 7;
  int f_s = sm >> 4, c_s = sm & 15;
  const uint32_t* brow = in_bits + (size_t)(m0 + sm) * KW;
  int wbase = ((h * 8 + f_s) * 64 + c_s) * 8;   // + kb2*16*8

  f32x4 acc[8] = {{0.f,0.f,0.f,0.f},{0.f,0.f,0.f,0.f},
                  {0.f,0.f,0.f,0.f},{0.f,0.f,0.f,0.f},
                  {0.f,0.f,0.f,0.f},{0.f,0.f,0.f,0.f},
                  {0.f,0.f,0.f,0.f},{0.f,0.f,0.f,0.f}};

  {  // stage chunk 0
    uint32_t w0 = brow[h];
#pragma unroll
    for (int kb2 = 0; kb2 < 4; ++kb2)
      *(short8v*)&A_lds[0][wbase + kb2*128] = expand8((w0 >> (kb2*8)) & 0xFFu);
  }
  __syncthreads();

  for (int kc = 0; kc < 48; ++kc) {   // 64 k per chunk
    int cur = kc & 1;
    if (kc + 1 < 48) {
      uint32_t w0 = brow[(kc + 1) * 2 + h];
#pragma unroll
      for (int kb2 = 0; kb2 < 4; ++kb2)
        *(short8v*)&A_lds[cur ^ 1][wbase + kb2*128] =
            expand8((w0 >> (kb2*8)) & 0xFFu);
    }
#pragma unroll
    for (int s = 0; s < 2; ++s) {
      size_t ks = (size_t)(kc * 2 + s);
      short8v B0 = *(const short8v*)&bh[ks * 512 + lane * 8];
      short8v B1 = *(const short8v*)&bm[ks * 512 + lane * 8];
      short8v B2 = *(const short8v*)&bl[ks * 512 + lane * 8];
      short8v A[8];
#pragma unroll
      for (int f = 0; f < 8; ++f)
        A[f] = *(const short8v*)&A_lds[cur][((s*8 + f) * 64 + lane) * 8];
#pragma unroll
      for (int f = 0; f < 8; ++f) acc[f] = MFMA(A[f], B0, acc[f]);
#pragma unroll
      for (int f = 0; f < 8; ++f) acc[f] = MFMA(A[f], B1, acc[f]);
#pragma unroll
      for (int f = 0; f < 8; ++f) acc[f] = MFMA(A[f], B2, acc[f]);
    }
    __syncthreads();
  }

#pragma unroll
  for (int f = 0; f < 8; ++f)
#pragma unroll
    for (int r = 0; r < 4; ++r) {
      int m = m0 + f*16 + kb*4 + r;
      H[(size_t)m * HID + nt*16 + col] = acc[f][r];
    }
}

// ---------------- LIF scan over t (the only sequential part) ---------------
__global__ __launch_bounds__(256) void lif_scan(
    const float* __restrict__ H,           // [5120][2048]
    uint8_t* __restrict__ spk) {           // [T][512][256] bit-packed along n
  int idx  = blockIdx.x * 256 + threadIdx.x;   // 0 .. 512*2048-1
  int b = idx >> 11, n = idx & 2047;
  int lane = threadIdx.x & 63;
  size_t spk_off = (size_t)b * 256 + (size_t)((n >> 3) & ~7);
  float v = 0.f;
#pragma unroll
  for (int t = 0; t < T_STEPS; ++t) {
    float h = H[(size_t)(t * B_SZ + b) * HID + n];
    bool fire;
    {
#pragma clang fp contract(off)
      float vd = v * 0.3f;
      float vn = vd + h;
      fire = (vn >= 1.0f);
      v = fire ? 0.0f : vn;
    }
    unsigned long long mask = __ballot(fire);
    if (lane == 0)
      *(unsigned long long*)&spk[(size_t)t * (512*256) + spk_off] = mask;
  }
}

// ---------------- output layer: one block per (n-tile, m-tile, t) ----------
__global__ __launch_bounds__(256) void out_mfma(
    const ushort* __restrict__ Ohi, const ushort* __restrict__ Omid,
    const ushort* __restrict__ Olo,
    const uint8_t* __restrict__ spk,        // [T][512][256]
    const float* __restrict__ bout,
    float* __restrict__ s) {                // [512][512], pre-zeroed
  int t   = blockIdx.z;
  int tid = threadIdx.x;
  int wave = tid >> 6, lane = tid & 63;
  int col  = lane & 15, kb = lane >> 4;
  int nt = blockIdx.x * 4 + wave;
  int m0 = blockIdx.y * 64;
  const ushort* bh = Ohi  + (size_t)nt * (HID/32) * 512;
  const ushort* bm = Omid + (size_t)nt * (HID/32) * 512;
  const ushort* bl = Olo  + (size_t)nt * (HID/32) * 512;
  const uint8_t* st = spk + (size_t)t * (512*256);

  f32x4 acc[4] = {{0.f,0.f,0.f,0.f},{0.f,0.f,0.f,0.f},
                  {0.f,0.f,0.f,0.f},{0.f,0.f,0.f,0.f}};
  for (int kc4 = 0; kc4 < 16; ++kc4) {      // K = 2048 = 16 * 4 * 32
    u32x4 aw[4];
#pragma unroll
    for (int f = 0; f < 4; ++f)
      aw[f] = *(const u32x4*)&st[(size_t)(m0 + f*16 + col) * 256 + kc4*16];
#pragma unroll
    for (int sv = 0; sv < 4; ++sv) {
      size_t ks = (size_t)(kc4 * 4 + sv);
      short8v B0 = *(const short8v*)&bh[ks * 512 + lane * 8];
      short8v B1 = *(const short8v*)&bm[ks * 512 + lane * 8];
      short8v B2 = *(const short8v*)&bl[ks * 512 + lane * 8];
      short8v A[4];
#pragma unroll
      for (int f = 0; f < 4; ++f)
        A[f] = expand8((aw[f][sv] >> (kb*8)) & 0xFFu);
#pragma unroll
      for (int f = 0; f < 4; ++f) acc[f] = MFMA(A[f], B0, acc[f]);
#pragma unroll
      for (int f = 0; f < 4; ++f) acc[f] = MFMA(A[f], B1, acc[f]);
#pragma unroll
      for (int f = 0; f < 4; ++f) acc[f] = MFMA(A[f], B2, acc[f]);
    }
  }
  float bo = bout[nt*16 + col];
#pragma unroll
  for (int f = 0; f < 4; ++f) {
#pragma unroll
    for (int r = 0; r < 4; ++r) {
      float out = acc[f][r] + bo;
      if (out > 0.0f) {
        int b = m0 + f*16 + kb*4 + r;
        atomicAdd(&s[(size_t)b * OUT_SZ + nt*16 + col], 1.0f);
      }
    }
  }
}

// ---------------------------------------------------------------------------
extern "C" void kernel_launch(void* const* d_in, const int* in_sizes, int n_in,
                              void* d_out, int out_size, void* d_ws, size_t ws_size,
                              hipStream_t stream) {
  const float* x    = (const float*)d_in[0];
  const float* Win  = (const float*)d_in[1];   // [2048][3072]
  const float* Wout = (const float*)d_in[2];   // [512][2048]
  const float* bout = (const float*)d_in[3];
  float* s = (float*)d_out;                    // [512][512]

  char* ws = (char*)d_ws;
  ushort* Whi  = (ushort*)(ws + 0);            // 3 x 12582912
  ushort* Wmid = (ushort*)(ws + 12582912);
  ushort* Wlo  = (ushort*)(ws + 25165824);
  ushort* Ohi  = (ushort*)(ws + 37748736);     // 3 x 2097152
  ushort* Omid = (ushort*)(ws + 39845888);
  ushort* Olo  = (ushort*)(ws + 41943040);
  uint32_t* in_bits = (uint32_t*)(ws + 44040192);  // 10*512*96*4 = 1966080
  uint8_t*  spk     = (uint8_t*)(ws + 46006272);   // 10*512*256  = 1310720
  float*    H       = (float*)(ws + 47316992);     // 5120*2048*4 = 41943040

  Keys hk;
  for (int t = 0; t < T_STEPS; ++t) {
    uint32_t y0, y1;
    threefry2x32(0u, 42u, 0u, (uint32_t)t, y0, y1);
    hk.k[2*t] = y0; hk.k[2*t+1] = y1;
  }

  (void)hipMemsetAsync(d_out, 0, (size_t)OUT_SZ * B_SZ * sizeof(float), stream);
  hipLaunchKernelGGL(split_frag, dim3(IN_SZ/256, HID), dim3(256), 0, stream,
                     Win, Whi, Wmid, Wlo, IN_SZ);
  hipLaunchKernelGGL(split_frag, dim3(HID/256, OUT_SZ), dim3(256), 0, stream,
                     Wout, Ohi, Omid, Olo, HID);
  hipLaunchKernelGGL(spikegen_kernel, dim3(NELEM/256), dim3(256), 0, stream,
                     x, in_bits, hk);
  hipLaunchKernelGGL(gemm_hidden, dim3(HID/64, M_ALL/128), dim3(256), 0, stream,
                     Whi, Wmid, Wlo, in_bits, H);
  hipLaunchKernelGGL(lif_scan, dim3((B_SZ*HID)/256), dim3(256), 0, stream,
                     H, spk);
  hipLaunchKernelGGL(out_mfma, dim3(OUT_SZ/64, B_SZ/64, T_STEPS), dim3(256), 0,
                     stream, Ohi, Omid, Olo, spk, bout, s);
}

// Round 6
// 264.383 us; speedup vs baseline: 8.7093x; 1.0697x over previous
//
#include <hip/hip_runtime.h>
#include <cstdint>

#define B_SZ   512
#define IN_SZ  3072
#define HID    2048
#define OUT_SZ 512
#define T_STEPS 10
#define NELEM  (512u*3072u)
#define KW     96                    // in_bits words per row
#define BITS_T_STRIDE (512u*96u)
#define M_ALL  (T_STEPS * B_SZ)      // 5120 rows in the de-fused hidden GEMM

typedef __attribute__((ext_vector_type(8))) short short8v;   // 8 bf16
typedef __attribute__((ext_vector_type(4))) float f32x4;
typedef __attribute__((ext_vector_type(4))) unsigned int u32x4;

struct Keys { uint32_t k[2*T_STEPS]; };

__host__ __device__ inline void threefry2x32(uint32_t k0, uint32_t k1,
                                             uint32_t x0, uint32_t x1,
                                             uint32_t& y0, uint32_t& y1) {
  const uint32_t ks2 = k0 ^ k1 ^ 0x1BD11BDAu;
#define TF_R(r) { x0 += x1; x1 = (x1 << (r)) | (x1 >> (32-(r))); x1 ^= x0; }
  x0 += k0; x1 += k1;
  TF_R(13) TF_R(15) TF_R(26) TF_R(6)   x0 += k1;  x1 += ks2 + 1u;
  TF_R(17) TF_R(29) TF_R(16) TF_R(24)  x0 += ks2; x1 += k0  + 2u;
  TF_R(13) TF_R(15) TF_R(26) TF_R(6)   x0 += k0;  x1 += k1  + 3u;
  TF_R(17) TF_R(29) TF_R(16) TF_R(24)  x0 += k1;  x1 += ks2 + 4u;
  TF_R(13) TF_R(15) TF_R(26) TF_R(6)   x0 += ks2; x1 += k0  + 5u;
#undef TF_R
  y0 = x0; y1 = x1;
}

// ---------------- spike generation (verified rounds 1/3/4/5) ---------------
__global__ __launch_bounds__(256) void spikegen_kernel(
    const float* __restrict__ x, uint32_t* __restrict__ pre_bits, Keys keys) {
  uint32_t m = blockIdx.x * 256u + threadIdx.x;
  uint32_t b = m / IN_SZ;
  uint32_t j = m - b * IN_SZ;
  float xv = x[m];
  float p = (float)(1.0 / (1.0 + exp(-(double)xv)));
  uint32_t lane = threadIdx.x & 63u;
  uint32_t wbase = b * KW + (j >> 5);
#pragma unroll
  for (int t = 0; t < T_STEPS; ++t) {
    uint32_t y0, y1;
    threefry2x32(keys.k[2*t], keys.k[2*t+1], 0u, m, y0, y1);
    uint32_t bits = y0 ^ y1;
    float u = __uint_as_float((bits >> 9) | 0x3f800000u) - 1.0f;
    unsigned long long mask = __ballot(u < p);
    if (lane == 0u) {
      *reinterpret_cast<unsigned long long*>(
          &pre_bits[(uint32_t)t * BITS_T_STRIDE + wbase]) = mask;
    }
  }
}

// ---------------- exact 3-way bf16 split, INTERLEAVED fragment layout ------
// out[nt][ks][split][512] : entry (kb*16+c)*8+e holds W[nt*16+c][ks*32+kb*8+e]
// thread <-> (ks2 = tid>>6, kb = (tid>>4)&3, c = tid&15):
//   reads 8 consecutive f32 (two float4), writes three contiguous 16B chunks;
//   a wave's 64 writes form one contiguous 1KB store per split.
__device__ __forceinline__ ushort rne_bf16(float f) {
  uint32_t u = __float_as_uint(f);
  return (ushort)((u + 0x7FFFu + ((u >> 16) & 1u)) >> 16);
}

__global__ __launch_bounds__(256) void split_frag(
    const float* __restrict__ W, ushort* __restrict__ out, int K) {
  int tid = threadIdx.x;
  int ks  = blockIdx.x * 4 + (tid >> 6);
  int kb  = (tid >> 4) & 3, c = tid & 15;
  int nt  = blockIdx.y;
  const float* src = &W[(size_t)(nt * 16 + c) * K + ks * 32 + kb * 8];
  float w8[8];
  *(f32x4*)&w8[0] = *(const f32x4*)&src[0];
  *(f32x4*)&w8[4] = *(const f32x4*)&src[4];
  union { ushort u[8]; short8v v; } h8, m8, l8;
#pragma unroll
  for (int j = 0; j < 8; ++j) {
    float w = w8[j];
    ushort h = rne_bf16(w);
    float hf = __uint_as_float((uint32_t)h << 16);
    float r1 = w - hf;                     // exact
    ushort m = rne_bf16(r1);
    float mf = __uint_as_float((uint32_t)m << 16);
    float r2 = r1 - mf;                    // exact
    ushort l = rne_bf16(r2);               // exact
    h8.u[j] = h; m8.u[j] = m; l8.u[j] = l;
  }
  size_t base = ((size_t)nt * (K / 32) + ks) * (3 * 512) + (kb * 16 + c) * 8;
  *(short8v*)&out[base]        = h8.v;
  *(short8v*)&out[base + 512]  = m8.v;
  *(short8v*)&out[base + 1024] = l8.v;
}

// ---------------- bit byte -> 8 bf16 {0,1} ---------------------------------
__device__ __forceinline__ short8v expand8(uint32_t b) {
  union { uint32_t u[4]; short8v v; } r;
#pragma unroll
  for (int j = 0; j < 4; ++j) {
    uint32_t x = b >> (2*j);
    r.u[j] = ((x & 1u) | ((x & 2u) << 15)) * 0x3F80u;  // bf16 1.0 per set bit
  }
  return r.v;
}

#define MFMA(a, b, c) __builtin_amdgcn_mfma_f32_16x16x32_bf16((a), (b), (c), 0, 0, 0)

// ---------------- hidden GEMM: H = pre @ Win^T, BM=128, XCD-swizzled -------
// 1-D grid 1280 = 8 XCD x 4 xb x 40 mb; each XCD owns a 256-col B panel
// (4 xb x 64 cols, 4.7 MB interleaved) reused by its 160 resident blocks.
__global__ __launch_bounds__(256) void gemm_hidden(
    const ushort* __restrict__ Wfrag,       // [128][96][3][512]
    const uint32_t* __restrict__ in_bits,   // [5120][96]
    float* __restrict__ H) {                // [5120][2048]
  __shared__ ushort A_lds[2][8192];         // 2 buf x 128 rows x 64 k = 32 KB
  int lin = blockIdx.x;
  int xcd = lin & 7, w = lin >> 3;
  int xb  = xcd * 4 + (w / 40);             // n-block (64 cols)
  int mb  = w % 40;                         // m-block (128 rows)
  int tid  = threadIdx.x;
  int wave = tid >> 6, lane = tid & 63;
  int col  = lane & 15, kb = lane >> 4;
  int nt = xb * 4 + wave;
  int m0 = mb * 128;
  const ushort* bp = Wfrag + (size_t)nt * (96 * 3 * 512);

  // staging role: thread = (half h, row sm); expands one 32-bit word per chunk
  int sm = tid & 127, h = tid >> 7;
  int f_s = sm >> 4, c_s = sm & 15;
  const uint32_t* brow = in_bits + (size_t)(m0 + sm) * KW;
  int wbase = ((h * 8 + f_s) * 64 + c_s) * 8;   // + kb2*128

  f32x4 acc[8] = {{0.f,0.f,0.f,0.f},{0.f,0.f,0.f,0.f},
                  {0.f,0.f,0.f,0.f},{0.f,0.f,0.f,0.f},
                  {0.f,0.f,0.f,0.f},{0.f,0.f,0.f,0.f},
                  {0.f,0.f,0.f,0.f},{0.f,0.f,0.f,0.f}};

  {  // stage chunk 0
    uint32_t w0 = brow[h];
#pragma unroll
    for (int kb2 = 0; kb2 < 4; ++kb2)
      *(short8v*)&A_lds[0][wbase + kb2*128] = expand8((w0 >> (kb2*8)) & 0xFFu);
  }
  __syncthreads();

  for (int kc = 0; kc < 48; ++kc) {   // 64 k per chunk
    int cur = kc & 1;
    if (kc + 1 < 48) {
      uint32_t w0 = brow[(kc + 1) * 2 + h];
#pragma unroll
      for (int kb2 = 0; kb2 < 4; ++kb2)
        *(short8v*)&A_lds[cur ^ 1][wbase + kb2*128] =
            expand8((w0 >> (kb2*8)) & 0xFFu);
    }
#pragma unroll
    for (int s = 0; s < 2; ++s) {
      const ushort* bks = bp + (size_t)(kc * 2 + s) * (3 * 512) + lane * 8;
      short8v B0 = *(const short8v*)&bks[0];
      short8v B1 = *(const short8v*)&bks[512];
      short8v B2 = *(const short8v*)&bks[1024];
      short8v A[8];
#pragma unroll
      for (int f = 0; f < 8; ++f)
        A[f] = *(const short8v*)&A_lds[cur][((s*8 + f) * 64 + lane) * 8];
#pragma unroll
      for (int f = 0; f < 8; ++f) acc[f] = MFMA(A[f], B0, acc[f]);
#pragma unroll
      for (int f = 0; f < 8; ++f) acc[f] = MFMA(A[f], B1, acc[f]);
#pragma unroll
      for (int f = 0; f < 8; ++f) acc[f] = MFMA(A[f], B2, acc[f]);
    }
    __syncthreads();
  }

#pragma unroll
  for (int f = 0; f < 8; ++f)
#pragma unroll
    for (int r = 0; r < 4; ++r) {
      int m = m0 + f*16 + kb*4 + r;
      H[(size_t)m * HID + nt*16 + col] = acc[f][r];
    }
}

// ---------------- LIF scan over t (the only sequential part) ---------------
__global__ __launch_bounds__(256) void lif_scan(
    const float* __restrict__ H,           // [5120][2048]
    uint8_t* __restrict__ spk) {           // [T][512][256] bit-packed along n
  int idx  = blockIdx.x * 256 + threadIdx.x;   // 0 .. 512*2048-1
  int b = idx >> 11, n = idx & 2047;
  int lane = threadIdx.x & 63;
  size_t spk_off = (size_t)b * 256 + (size_t)((n >> 3) & ~7);
  float v = 0.f;
#pragma unroll
  for (int t = 0; t < T_STEPS; ++t) {
    float h = H[(size_t)(t * B_SZ + b) * HID + n];
    bool fire;
    {
#pragma clang fp contract(off)
      float vd = v * 0.3f;
      float vn = vd + h;
      fire = (vn >= 1.0f);
      v = fire ? 0.0f : vn;
    }
    unsigned long long mask = __ballot(fire);
    if (lane == 0)
      *(unsigned long long*)&spk[(size_t)t * (512*256) + spk_off] = mask;
  }
}

// ---------------- output layer, XCD-swizzled: each XCD pins one n-panel ----
// 1-D grid 640 = 8 XCD(x) x 8(y) x 10(t); Wout panel per XCD = 0.79 MB.
__global__ __launch_bounds__(256) void out_mfma(
    const ushort* __restrict__ Ofrag,       // [32][64][3][512]
    const uint8_t* __restrict__ spk,        // [T][512][256]
    const float* __restrict__ bout,
    float* __restrict__ s) {                // [512][512], pre-zeroed
  int lin = blockIdx.x;
  int x = lin & 7;
  int r0 = lin >> 3;
  int y = r0 & 7;
  int t = r0 >> 3;
  int tid = threadIdx.x;
  int wave = tid >> 6, lane = tid & 63;
  int col  = lane & 15, kb = lane >> 4;
  int nt = x * 4 + wave;
  int m0 = y * 64;
  const ushort* bp = Ofrag + (size_t)nt * (64 * 3 * 512);
  const uint8_t* st = spk + (size_t)t * (512*256);

  f32x4 acc[4] = {{0.f,0.f,0.f,0.f},{0.f,0.f,0.f,0.f},
                  {0.f,0.f,0.f,0.f},{0.f,0.f,0.f,0.f}};
  for (int kc4 = 0; kc4 < 16; ++kc4) {      // K = 2048 = 16 * 4 * 32
    u32x4 aw[4];
#pragma unroll
    for (int f = 0; f < 4; ++f)
      aw[f] = *(const u32x4*)&st[(size_t)(m0 + f*16 + col) * 256 + kc4*16];
#pragma unroll
    for (int sv = 0; sv < 4; ++sv) {
      const ushort* bks = bp + (size_t)(kc4 * 4 + sv) * (3 * 512) + lane * 8;
      short8v B0 = *(const short8v*)&bks[0];
      short8v B1 = *(const short8v*)&bks[512];
      short8v B2 = *(const short8v*)&bks[1024];
      short8v A[4];
#pragma unroll
      for (int f = 0; f < 4; ++f)
        A[f] = expand8((aw[f][sv] >> (kb*8)) & 0xFFu);
#pragma unroll
      for (int f = 0; f < 4; ++f) acc[f] = MFMA(A[f], B0, acc[f]);
#pragma unroll
      for (int f = 0; f < 4; ++f) acc[f] = MFMA(A[f], B1, acc[f]);
#pragma unroll
      for (int f = 0; f < 4; ++f) acc[f] = MFMA(A[f], B2, acc[f]);
    }
  }
  float bo = bout[nt*16 + col];
#pragma unroll
  for (int f = 0; f < 4; ++f) {
#pragma unroll
    for (int r = 0; r < 4; ++r) {
      float out = acc[f][r] + bo;
      if (out > 0.0f) {
        int b = m0 + f*16 + kb*4 + r;
        atomicAdd(&s[(size_t)b * OUT_SZ + nt*16 + col], 1.0f);
      }
    }
  }
}

// ---------------------------------------------------------------------------
extern "C" void kernel_launch(void* const* d_in, const int* in_sizes, int n_in,
                              void* d_out, int out_size, void* d_ws, size_t ws_size,
                              hipStream_t stream) {
  const float* x    = (const float*)d_in[0];
  const float* Win  = (const float*)d_in[1];   // [2048][3072]
  const float* Wout = (const float*)d_in[2];   // [512][2048]
  const float* bout = (const float*)d_in[3];
  float* s = (float*)d_out;                    // [512][512]

  char* ws = (char*)d_ws;
  ushort*   Wfrag   = (ushort*)(ws + 0);           // 128*96*3*512*2 = 37748736
  ushort*   Ofrag   = (ushort*)(ws + 37748736);    // 32*64*3*512*2  = 6291456
  uint32_t* in_bits = (uint32_t*)(ws + 44040192);  // 10*512*96*4    = 1966080
  uint8_t*  spk     = (uint8_t*)(ws + 46006272);   // 10*512*256     = 1310720
  float*    H       = (float*)(ws + 47316992);     // 5120*2048*4    = 41943040

  Keys hk;
  for (int t = 0; t < T_STEPS; ++t) {
    uint32_t y0, y1;
    threefry2x32(0u, 42u, 0u, (uint32_t)t, y0, y1);
    hk.k[2*t] = y0; hk.k[2*t+1] = y1;
  }

  (void)hipMemsetAsync(d_out, 0, (size_t)OUT_SZ * B_SZ * sizeof(float), stream);
  hipLaunchKernelGGL(split_frag, dim3(IN_SZ/128, HID/16), dim3(256), 0, stream,
                     Win, Wfrag, IN_SZ);
  hipLaunchKernelGGL(split_frag, dim3(HID/128, OUT_SZ/16), dim3(256), 0, stream,
                     Wout, Ofrag, HID);
  hipLaunchKernelGGL(spikegen_kernel, dim3(NELEM/256), dim3(256), 0, stream,
                     x, in_bits, hk);
  hipLaunchKernelGGL(gemm_hidden, dim3(8 * 4 * 40), dim3(256), 0, stream,
                     Wfrag, in_bits, H);
  hipLaunchKernelGGL(lif_scan, dim3((B_SZ*HID)/256), dim3(256), 0, stream,
                     H, spk);
  hipLaunchKernelGGL(out_mfma, dim3(8 * 8 * T_STEPS), dim3(256), 0, stream,
                     Ofrag, spk, bout, s);
}